// Round 2
// baseline (1036.197 us; speedup 1.0000x reference)
//
#include <hip/hip_runtime.h>

#define NBLK 64
#define NTHR 256

typedef __bf16 bf16x8 __attribute__((ext_vector_type(8)));
typedef float  f32x4  __attribute__((ext_vector_type(4)));

__device__ __forceinline__ unsigned short f2bf(float f) {
  unsigned int u = __float_as_uint(f);
  return (unsigned short)((u + 0x7fffu + ((u >> 16) & 1u)) >> 16);  // RNE
}

__device__ __forceinline__ bf16x8 asbf(uint4 u) {
  return __builtin_bit_cast(bf16x8, u);
}

__device__ __forceinline__ float sigf(float xv) { return 1.0f / (1.0f + __expf(-xv)); }

// ws layout (bytes):
//   WCAT  bf16 [2][4096][2048]   K-concat [W_ih | W_hh], 33554432 B
//   OUTB  bf16 [2][32][1024]     parity ping-pong of "out" (cell input)
//   HBB   bf16 [2][2][32][1024]  [t-parity][layer] h for GEMM
//   HST   f32  [2][32][1024]     fp32 h state (zoneout chain)
//   CST   f32  [2][32][1024]     fp32 c state
//   SSE   f32
#define WS_WCAT 0
#define WS_OUTB 33554432
#define WS_HBB  (WS_OUTB + 131072)
#define WS_HST  (WS_HBB + 262144)
#define WS_CST  (WS_HST + 262144)
#define WS_SSE  (WS_CST + 262144)

// ---------------- prep: weights -> bf16, init activations/state ----------------
__global__ void prep_kernel(const float* __restrict__ x, const float* __restrict__ h0,
                            const float* __restrict__ c0,
                            const float* __restrict__ Wih, const float* __restrict__ Whh,
                            unsigned char* __restrict__ ws)
{
  unsigned short* Wcat = (unsigned short*)(ws + WS_WCAT);
  unsigned short* outb = (unsigned short*)(ws + WS_OUTB);
  unsigned short* hbb  = (unsigned short*)(ws + WS_HBB);
  float*          hst  = (float*)(ws + WS_HST);
  float*          cst  = (float*)(ws + WS_CST);
  float*          sse  = (float*)(ws + WS_SSE);

  int gid = blockIdx.x * blockDim.x + threadIdx.x;
  int stride = gridDim.x * blockDim.x;

  // weights: rows are (l*4096 + n), k-concat [Wih row | Whh row], 4 floats per idx
  for (int e4 = gid; e4 < 4194304; e4 += stride) {
    int row = e4 >> 9;            // 0..8191
    int k4  = e4 & 511;           // float4 index within 2048-wide concat row
    const float* src = (k4 < 256)
        ? (Wih + (size_t)row * 1024 + (size_t)k4 * 4)
        : (Whh + (size_t)row * 1024 + (size_t)(k4 - 256) * 4);
    float4 v = *(const float4*)src;
    ushort4 o;
    o.x = f2bf(v.x); o.y = f2bf(v.y); o.z = f2bf(v.z); o.w = f2bf(v.w);
    *(ushort4*)(Wcat + (size_t)row * 2048 + (size_t)k4 * 4) = o;
  }
  for (int i = gid; i < 32768; i += stride) outb[i] = f2bf(x[i]);   // parity 0 = x
  for (int i = gid; i < 65536; i += stride) {
    float h = h0[i];
    hbb[i] = f2bf(h);            // t-parity 0, both layers
    hst[i] = h;
    cst[i] = c0[i];
  }
  if (gid == 0) *sse = 0.0f;
}

// ---------------- one LSTM cell (t,l): GEMM + pointwise ----------------
__global__ void __launch_bounds__(NTHR, 1)
cell_kernel(const float* __restrict__ hmask, const float* __restrict__ cmask,
            const float* __restrict__ labels,
            const float* __restrict__ bih, const float* __restrict__ bhh,
            float* __restrict__ out, unsigned char* __restrict__ ws, int ci)
{
  const int t = ci >> 1;
  const int l = ci & 1;
  const int tid = threadIdx.x;
  const int bid = blockIdx.x;
  const int j0  = bid * 16;

  unsigned short* Wcat = (unsigned short*)(ws + WS_WCAT);
  unsigned short* outb = (unsigned short*)(ws + WS_OUTB);
  unsigned short* hbb  = (unsigned short*)(ws + WS_HBB);
  float*          hst  = (float*)(ws + WS_HST);
  float*          cst  = (float*)(ws + WS_CST);
  float*          sse  = (float*)(ws + WS_SSE);

  __shared__ __align__(16) unsigned short As[32 * 520];   // A chunk: 32 x 512, pad 520
  __shared__ float Ps[4 * 544];                           // [gate][m*17 + c]

  // wave geometry
  const int lane = tid & 63;
  const int wid  = tid >> 6;
  const int q    = lane >> 4;
  const int m0   = lane & 15;
  const int gp   = wid & 1;         // gate pair 0:{i,f} 1:{g,o}
  const int kh   = wid >> 1;        // K-half of each 512 chunk
  const int r_s  = tid >> 3;        // staging row
  const int seg  = tid & 7;

  for (int i = tid; i < 4 * 544; i += NTHR) Ps[i] = 0.0f;

  const unsigned short* outc = outb + l * 32768;                   // read parity == l
  const unsigned short* hbc  = hbb + ((t & 1) * 2 + l) * 32768;    // t-parity, layer

  f32x4 acc00 = {0.f,0.f,0.f,0.f}, acc10 = {0.f,0.f,0.f,0.f};
  f32x4 acc01 = {0.f,0.f,0.f,0.f}, acc11 = {0.f,0.f,0.f,0.f};

  const unsigned short* w0base =
      Wcat + ((size_t)(l * 4096 + (2 * gp) * 1024 + j0 + m0)) * 2048 + kh * 256 + q * 8;

  // register double-buffered A staging, K-chunks of 512 (k<1024: out, else h)
  uint4 stg[8];
  {
    const unsigned short* sp = outc + r_s * 1024;
#pragma unroll
    for (int it = 0; it < 8; ++it) stg[it] = *(const uint4*)(sp + seg * 8 + it * 64);
  }
  for (int kc = 0; kc < 4; ++kc) {
    __syncthreads();
#pragma unroll
    for (int it = 0; it < 8; ++it)
      *(uint4*)&As[r_s * 520 + seg * 8 + it * 64] = stg[it];
    __syncthreads();
    if (kc < 3) {
      int kn = kc + 1;
      const unsigned short* sp = (kn < 2) ? (outc + r_s * 1024 + kn * 512)
                                          : (hbc  + r_s * 1024 + (kn - 2) * 512);
#pragma unroll
      for (int it = 0; it < 8; ++it) stg[it] = *(const uint4*)(sp + seg * 8 + it * 64);
    }
    const unsigned short* wp = w0base + (size_t)kc * 512;
#pragma unroll
    for (int ks = 0; ks < 8; ++ks) {
      int kl = kh * 256 + ks * 32 + q * 8;
      bf16x8 a0 = asbf(*(const uint4*)&As[m0 * 520 + kl]);
      bf16x8 a1 = asbf(*(const uint4*)&As[(m0 + 16) * 520 + kl]);
      bf16x8 b0 = asbf(*(const uint4*)(wp + ks * 32));
      bf16x8 b1 = asbf(*(const uint4*)(wp + (size_t)1024 * 2048 + ks * 32));
      acc00 = __builtin_amdgcn_mfma_f32_16x16x32_bf16(a0, b0, acc00, 0, 0, 0);
      acc10 = __builtin_amdgcn_mfma_f32_16x16x32_bf16(a1, b0, acc10, 0, 0, 0);
      acc01 = __builtin_amdgcn_mfma_f32_16x16x32_bf16(a0, b1, acc01, 0, 0, 0);
      acc11 = __builtin_amdgcn_mfma_f32_16x16x32_bf16(a1, b1, acc11, 0, 0, 0);
    }
  }
  // split-K reduction: 2 atomic adds per slot (kh=0,1), deterministic count
  {
    int g0 = 2 * gp, g1 = g0 + 1;
#pragma unroll
    for (int i = 0; i < 4; ++i) {
      int r0 = q * 4 + i;            // C/D: row = quad*4+reg, col = lane&15
      atomicAdd(&Ps[g0 * 544 + r0 * 17 + m0],        acc00[i]);
      atomicAdd(&Ps[g0 * 544 + (r0 + 16) * 17 + m0], acc10[i]);
      atomicAdd(&Ps[g1 * 544 + r0 * 17 + m0],        acc01[i]);
      atomicAdd(&Ps[g1 * 544 + (r0 + 16) * 17 + m0], acc11[i]);
    }
  }
  __syncthreads();

  // pointwise: this thread owns (ma, c_) and (ma+16, c_)
  const int c_ = tid & 15;
  const int ma = tid >> 4;
  const int jg = j0 + c_;

  int mbase = ((t * 2 + l) * 32 + ma) * 1024 + jg;
  float hm0 = hmask[mbase], hm1 = hmask[mbase + 16384];
  float cm0 = cmask[mbase], cm1 = cmask[mbase + 16384];

  float bv[4];
#pragma unroll
  for (int g = 0; g < 4; ++g) {
    int n = l * 4096 + g * 1024 + jg;
    bv[g] = bih[n] + bhh[n];
  }

  float local_sse = 0.0f;
#pragma unroll
  for (int hf = 0; hf < 2; ++hf) {
    int m = ma + hf * 16;
    int sidx = l * 32768 + m * 1024 + jg;
    float gi = Ps[0 * 544 + m * 17 + c_] + bv[0];
    float gf = Ps[1 * 544 + m * 17 + c_] + bv[1];
    float gg = Ps[2 * 544 + m * 17 + c_] + bv[2];
    float go = Ps[3 * 544 + m * 17 + c_] + bv[3];
    float ii = sigf(gi), ff = sigf(gf), oo = sigf(go);
    float gt = tanhf(gg);
    float cprev = cst[sidx], hprev = hst[sidx];
    float ccand = ff * cprev + ii * gt;
    float hcand = oo * tanhf(ccand);
    float hmv = hf ? hm1 : hm0;
    float cmv = hf ? cm1 : cm0;
    float hnew = hmv * hprev + (1.0f - hmv) * hcand;
    float cnew = cmv * cprev + (1.0f - cmv) * ccand;
    cst[sidx] = cnew;
    hst[sidx] = hnew;
    unsigned short ub = f2bf(hnew);
    outb[(l ^ 1) * 32768 + m * 1024 + jg] = ub;                 // next cell's input
    hbb[(((t + 1) & 1) * 2 + l) * 32768 + m * 1024 + jg] = ub;  // next t, same layer
    if (l == 1) {
      out[(m * 16 + t) * 1024 + jg] = hnew;                     // ret[b][t][h]
      float d = hnew - labels[(m * 16 + t) * 1024 + jg];
      local_sse += d * d;
    }
  }
  if (l == 1) {
    float s = local_sse;
#pragma unroll
    for (int off = 32; off > 0; off >>= 1) s += __shfl_down(s, off);
    if (lane == 0) atomicAdd(sse, s);
  }
}

// ---------------- finalize: loss ----------------
__global__ void fin_kernel(float* __restrict__ out, unsigned char* __restrict__ ws) {
  if (blockIdx.x == 0 && threadIdx.x == 0)
    out[524288] = *(float*)(ws + WS_SSE) * (1.0f / 524288.0f);
}

extern "C" void kernel_launch(void* const* d_in, const int* in_sizes, int n_in,
                              void* d_out, int out_size, void* d_ws, size_t ws_size,
                              hipStream_t stream) {
  (void)in_sizes; (void)n_in; (void)out_size; (void)ws_size;
  const float* x   = (const float*)d_in[0];
  const float* h0  = (const float*)d_in[1];
  const float* c0  = (const float*)d_in[2];
  const float* hm  = (const float*)d_in[3];
  const float* cm  = (const float*)d_in[4];
  const float* lb  = (const float*)d_in[5];
  const float* wih = (const float*)d_in[6];
  const float* whh = (const float*)d_in[7];
  const float* bi  = (const float*)d_in[8];
  const float* bh  = (const float*)d_in[9];
  float* out = (float*)d_out;
  unsigned char* ws = (unsigned char*)d_ws;

  prep_kernel<<<dim3(1024), dim3(256), 0, stream>>>(x, h0, c0, wih, whh, ws);
  for (int ci = 0; ci < 32; ++ci)
    cell_kernel<<<dim3(NBLK), dim3(NTHR), 0, stream>>>(hm, cm, lb, bi, bh, out, ws, ci);
  fin_kernel<<<dim3(1), dim3(64), 0, stream>>>(out, ws);
}

// Round 3
// 566.623 us; speedup vs baseline: 1.8287x; 1.8287x over previous
//
#include <hip/hip_runtime.h>

#define NTHR 256

typedef __bf16 bf16x8 __attribute__((ext_vector_type(8)));
typedef float  f32x4  __attribute__((ext_vector_type(4)));

__device__ __forceinline__ unsigned short f2bf(float f) {
  unsigned int u = __float_as_uint(f);
  return (unsigned short)((u + 0x7fffu + ((u >> 16) & 1u)) >> 16);  // RNE
}

__device__ __forceinline__ bf16x8 asbf(uint4 u) {
  return __builtin_bit_cast(bf16x8, u);
}

__device__ __forceinline__ float sigf(float xv) { return 1.0f / (1.0f + __expf(-xv)); }

// ws layout (bytes):
//   WCAT  bf16 [2][4096][2048]   K-concat [W_ih | W_hh]          33554432
//   OUTB  bf16 [2][32][1024]     parity ping-pong of cell input    131072
//   HBB   bf16 [2][2][32][1024]  [t-parity][layer] h for GEMM      262144
//   HST   f32  [2][32][1024]     fp32 h state                      262144
//   CST   f32  [2][32][1024]     fp32 c state                      262144
//   PS    f32  [64][4][32][16]   split-K gate partials             524288
//   FLG   int  [64]              split-K completion flags             256
//   BCB   f32  [2][4096]         combined bias                      32768
//   SSE   f32
#define WS_WCAT 0
#define WS_OUTB 33554432
#define WS_HBB  (WS_OUTB + 131072)
#define WS_HST  (WS_HBB + 262144)
#define WS_CST  (WS_HST + 262144)
#define WS_PS   (WS_CST + 262144)
#define WS_FLG  (WS_PS + 524288)
#define WS_BCB  (WS_FLG + 256)
#define WS_SSE  (WS_BCB + 32768)

// ---------------- prep ----------------
__global__ void prep_kernel(const float* __restrict__ x, const float* __restrict__ h0,
                            const float* __restrict__ c0,
                            const float* __restrict__ Wih, const float* __restrict__ Whh,
                            const float* __restrict__ bih, const float* __restrict__ bhh,
                            unsigned char* __restrict__ ws)
{
  unsigned short* Wcat = (unsigned short*)(ws + WS_WCAT);
  unsigned short* outb = (unsigned short*)(ws + WS_OUTB);
  unsigned short* hbb  = (unsigned short*)(ws + WS_HBB);
  float*          hst  = (float*)(ws + WS_HST);
  float*          cst  = (float*)(ws + WS_CST);
  float*          Ps   = (float*)(ws + WS_PS);
  int*            flg  = (int*)(ws + WS_FLG);
  float*          bcb  = (float*)(ws + WS_BCB);
  float*          sse  = (float*)(ws + WS_SSE);

  int gid = blockIdx.x * blockDim.x + threadIdx.x;
  int stride = gridDim.x * blockDim.x;

  // weights -> bf16, K-concat rows of 2048
  for (int e4 = gid; e4 < 4194304; e4 += stride) {
    int row = e4 >> 9;
    int k4  = e4 & 511;
    const float* src = (k4 < 256)
        ? (Wih + (size_t)row * 1024 + (size_t)k4 * 4)
        : (Whh + (size_t)row * 1024 + (size_t)(k4 - 256) * 4);
    float4 v = *(const float4*)src;
    ushort4 o;
    o.x = f2bf(v.x); o.y = f2bf(v.y); o.z = f2bf(v.z); o.w = f2bf(v.w);
    *(ushort4*)(Wcat + (size_t)row * 2048 + (size_t)k4 * 4) = o;
  }
  for (int i = gid; i < 32768; i += stride) outb[i] = f2bf(x[i]);   // parity 0 = x
  for (int i = gid; i < 65536; i += stride) {
    float h = h0[i];
    hbb[i] = f2bf(h);
    hst[i] = h;
    cst[i] = c0[i];
  }
  for (int i = gid; i < 131072; i += stride) Ps[i] = 0.0f;
  for (int i = gid; i < 8192; i += stride) bcb[i] = bih[i] + bhh[i];
  if (gid < 64) flg[gid] = 0;
  if (gid == 0) *sse = 0.0f;
}

// ---------------- one LSTM cell: 256-block split-K GEMM + last-block pointwise ----------------
__global__ void __launch_bounds__(NTHR, 1)
cell_kernel(const float* __restrict__ hmask, const float* __restrict__ cmask,
            const float* __restrict__ labels,
            float* __restrict__ out, unsigned char* __restrict__ ws, int ci)
{
  const int t = ci >> 1;
  const int l = ci & 1;
  const int tid = threadIdx.x;
  const int bid = blockIdx.x;
  const int g   = bid >> 2;          // H-column group (16 cols)
  const int kb  = bid & 3;           // K-quarter (512 of 2048)

  unsigned short* Wcat = (unsigned short*)(ws + WS_WCAT);
  unsigned short* outb = (unsigned short*)(ws + WS_OUTB);
  unsigned short* hbb  = (unsigned short*)(ws + WS_HBB);
  float*          hst  = (float*)(ws + WS_HST);
  float*          cst  = (float*)(ws + WS_CST);
  float*          Ps   = (float*)(ws + WS_PS);
  int*            flg  = (int*)(ws + WS_FLG);
  float*          bcb  = (float*)(ws + WS_BCB);
  float*          sse  = (float*)(ws + WS_SSE);

  __shared__ __align__(16) unsigned short As[32 * 520];   // 32 x 512 A-slice, pad 8
  __shared__ int lastflag;

  const int lane = tid & 63;
  const int wid  = tid >> 6;         // wave = gate
  const int q    = lane >> 4;
  const int m0   = lane & 15;

  // --- B prefetch: 16 outstanding dwordx4 per lane (64 KB/block) ---
  const unsigned short* wrow =
      Wcat + ((size_t)(l * 4096 + wid * 1024 + g * 16 + m0)) * 2048 + kb * 512 + q * 8;
  uint4 breg[16];
#pragma unroll
  for (int ks = 0; ks < 16; ++ks) breg[ks] = *(const uint4*)(wrow + ks * 32);

  // --- A staging: 32 KB to LDS ---
  const unsigned short* asrc = (kb < 2)
      ? (outb + l * 32768 + kb * 512)
      : (hbb + ((t & 1) * 2 + l) * 32768 + (kb - 2) * 512);
  {
    int r = tid >> 3, seg = tid & 7;
#pragma unroll
    for (int it = 0; it < 8; ++it) {
      uint4 v = *(const uint4*)(asrc + r * 1024 + seg * 64 + it * 8);
      *(uint4*)&As[r * 520 + seg * 64 + it * 8] = v;
    }
  }
  __syncthreads();

  // --- MFMA: this wave computes gate `wid`, 32 batch rows x 16 cols, K=512 ---
  f32x4 acc0 = {0.f,0.f,0.f,0.f}, acc1 = {0.f,0.f,0.f,0.f};
#pragma unroll
  for (int ks = 0; ks < 16; ++ks) {
    int kl = ks * 32 + q * 8;
    bf16x8 a0 = asbf(*(const uint4*)&As[m0 * 520 + kl]);
    bf16x8 a1 = asbf(*(const uint4*)&As[(m0 + 16) * 520 + kl]);
    bf16x8 b  = asbf(breg[ks]);
    acc0 = __builtin_amdgcn_mfma_f32_16x16x32_bf16(a0, b, acc0, 0, 0, 0);
    acc1 = __builtin_amdgcn_mfma_f32_16x16x32_bf16(a1, b, acc1, 0, 0, 0);
  }

  // --- split-K partial accumulation (device-scope fp32 atomics) ---
  float* pg = Ps + ((size_t)(g * 4 + wid) * 32) * 16 + m0;
#pragma unroll
  for (int i = 0; i < 4; ++i) {
    int r0 = q * 4 + i;              // C/D: row = quad*4+reg, col = lane&15
    unsafeAtomicAdd(pg + r0 * 16,        acc0[i]);
    unsafeAtomicAdd(pg + (r0 + 16) * 16, acc1[i]);
  }
  __syncthreads();                   // drains all vm ops of this block
  if (tid == 0)
    lastflag = __hip_atomic_fetch_add(&flg[g], 1, __ATOMIC_ACQ_REL, __HIP_MEMORY_SCOPE_AGENT);
  __syncthreads();
  if (lastflag != 3) return;         // not the last K-quarter to finish

  // --- last block of group: pointwise for 32 batch x 16 cols ---
  const int c_ = tid & 15;
  const int ma = tid >> 4;
  const int jg = g * 16 + c_;
  float* pgrp = Ps + (size_t)(g * 4) * 32 * 16;   // [gate][m][c], strides 512/16/1

  int mbase = ((t * 2 + l) * 32 + ma) * 1024 + jg;
  float hm0 = hmask[mbase], hm1 = hmask[mbase + 16384];
  float cm0 = cmask[mbase], cm1 = cmask[mbase + 16384];

  float bv[4];
#pragma unroll
  for (int gt = 0; gt < 4; ++gt) bv[gt] = bcb[l * 4096 + gt * 1024 + jg];

  float local_sse = 0.0f;
#pragma unroll
  for (int hf = 0; hf < 2; ++hf) {
    int m = ma + hf * 16;
    int sidx = l * 32768 + m * 1024 + jg;
    float gi = __hip_atomic_load(&pgrp[0 * 512 + m * 16 + c_], __ATOMIC_RELAXED, __HIP_MEMORY_SCOPE_AGENT) + bv[0];
    float gf = __hip_atomic_load(&pgrp[1 * 512 + m * 16 + c_], __ATOMIC_RELAXED, __HIP_MEMORY_SCOPE_AGENT) + bv[1];
    float gg = __hip_atomic_load(&pgrp[2 * 512 + m * 16 + c_], __ATOMIC_RELAXED, __HIP_MEMORY_SCOPE_AGENT) + bv[2];
    float go = __hip_atomic_load(&pgrp[3 * 512 + m * 16 + c_], __ATOMIC_RELAXED, __HIP_MEMORY_SCOPE_AGENT) + bv[3];
    float ii = sigf(gi), ff = sigf(gf), oo = sigf(go);
    float gt = tanhf(gg);
    float cprev = cst[sidx], hprev = hst[sidx];
    float ccand = ff * cprev + ii * gt;
    float hcand = oo * tanhf(ccand);
    float hmv = hf ? hm1 : hm0;
    float cmv = hf ? cm1 : cm0;
    float hnew = hmv * hprev + (1.0f - hmv) * hcand;
    float cnew = cmv * cprev + (1.0f - cmv) * ccand;
    cst[sidx] = cnew;
    hst[sidx] = hnew;
    unsigned short ub = f2bf(hnew);
    outb[(l ^ 1) * 32768 + m * 1024 + jg] = ub;                 // next cell's input
    hbb[(((t + 1) & 1) * 2 + l) * 32768 + m * 1024 + jg] = ub;  // next t, same layer
    if (l == 1) {
      out[(m * 16 + t) * 1024 + jg] = hnew;                     // ret[b][t][h]
      float d = hnew - labels[(m * 16 + t) * 1024 + jg];
      local_sse += d * d;
    }
  }
  if (l == 1) {
    float s = local_sse;
#pragma unroll
    for (int off = 32; off > 0; off >>= 1) s += __shfl_down(s, off);
    if (lane == 0) atomicAdd(sse, s);
  }

  // re-zero this group's partials + flag for the next cell (visible at kernel boundary)
  for (int i = tid; i < 2048; i += NTHR) pgrp[i] = 0.0f;
  if (tid == 0) flg[g] = 0;
}

// ---------------- finalize: loss ----------------
__global__ void fin_kernel(float* __restrict__ out, unsigned char* __restrict__ ws) {
  if (blockIdx.x == 0 && threadIdx.x == 0)
    out[524288] = *(float*)(ws + WS_SSE) * (1.0f / 524288.0f);
}

extern "C" void kernel_launch(void* const* d_in, const int* in_sizes, int n_in,
                              void* d_out, int out_size, void* d_ws, size_t ws_size,
                              hipStream_t stream) {
  (void)in_sizes; (void)n_in; (void)out_size; (void)ws_size;
  const float* x   = (const float*)d_in[0];
  const float* h0  = (const float*)d_in[1];
  const float* c0  = (const float*)d_in[2];
  const float* hm  = (const float*)d_in[3];
  const float* cm  = (const float*)d_in[4];
  const float* lb  = (const float*)d_in[5];
  const float* wih = (const float*)d_in[6];
  const float* whh = (const float*)d_in[7];
  const float* bi  = (const float*)d_in[8];
  const float* bh  = (const float*)d_in[9];
  float* out = (float*)d_out;
  unsigned char* ws = (unsigned char*)d_ws;

  prep_kernel<<<dim3(1024), dim3(256), 0, stream>>>(x, h0, c0, wih, whh, bi, bh, ws);
  for (int ci = 0; ci < 32; ++ci)
    cell_kernel<<<dim3(256), dim3(NTHR), 0, stream>>>(hm, cm, lb, out, ws, ci);
  fin_kernel<<<dim3(1), dim3(64), 0, stream>>>(out, ws);
}